// Round 7
// baseline (639.431 us; speedup 1.0000x reference)
//
#include <hip/hip_runtime.h>
#include <hip/hip_bf16.h>

#define N_NODES 50000
#define N_EDGES 800000
#define DIM 128
#define PAD 129  // transposed-LDS leading pad (breaks bank alignment)

static __device__ __forceinline__ unsigned short f2bf(float f) {
    unsigned int u = __float_as_uint(f);
    u += 0x7fffu + ((u >> 16) & 1u);  // round-to-nearest-even
    return (unsigned short)(u >> 16);
}

// ---------------------------------------------------------------------------
// Edge binning: histogram -> parallel exclusive scan -> bin scatter.
// ---------------------------------------------------------------------------
__global__ __launch_bounds__(256) void hist_dst(
    const int* __restrict__ dst, int* __restrict__ bins, int E)
{
    const int e = blockIdx.x * 256 + threadIdx.x;
    if (e < E) atomicAdd(&bins[dst[e]], 1);
}

__global__ __launch_bounds__(256) void scan_blocks(
    int* __restrict__ data, int* __restrict__ bsums, int n)
{
    __shared__ int ws[4];
    const int tid = threadIdx.x, lane = tid & 63, wid = tid >> 6;
    const int i = blockIdx.x * 256 + tid;
    const int x = (i < n) ? data[i] : 0;
    int v = x;
    #pragma unroll
    for (int off = 1; off < 64; off <<= 1) {
        const int t = __shfl_up(v, off);
        if (lane >= off) v += t;
    }
    if (lane == 63) ws[wid] = v;
    __syncthreads();
    const int w0 = ws[0], w1 = ws[1], w2 = ws[2];
    const int woff = (wid > 0 ? w0 : 0) + (wid > 1 ? w1 : 0) + (wid > 2 ? w2 : 0);
    const int incl = v + woff;
    if (i < n) data[i] = incl - x;
    if (tid == 255) bsums[blockIdx.x] = incl;
}

__global__ __launch_bounds__(256) void scan_bsums(int* __restrict__ bsums, int nb)
{
    __shared__ int ws[4];
    const int tid = threadIdx.x, lane = tid & 63, wid = tid >> 6;
    const int x = (tid < nb) ? bsums[tid] : 0;
    int v = x;
    #pragma unroll
    for (int off = 1; off < 64; off <<= 1) {
        const int t = __shfl_up(v, off);
        if (lane >= off) v += t;
    }
    if (lane == 63) ws[wid] = v;
    __syncthreads();
    const int w0 = ws[0], w1 = ws[1], w2 = ws[2];
    const int woff = (wid > 0 ? w0 : 0) + (wid > 1 ? w1 : 0) + (wid > 2 ? w2 : 0);
    if (tid < nb) bsums[tid] = (v + woff) - x;
}

__global__ __launch_bounds__(256) void scan_add(
    int* __restrict__ data, const int* __restrict__ bsums, int n)
{
    const int i = blockIdx.x * 256 + threadIdx.x;
    if (i < n) data[i] += bsums[blockIdx.x];
}

__global__ __launch_bounds__(256) void bin_edges(
    const int* __restrict__ src, const int* __restrict__ dst,
    const float* __restrict__ ew, int* __restrict__ bins,
    int2* __restrict__ binned, int E)
{
    const int e = blockIdx.x * 256 + threadIdx.x;
    if (e >= E) return;
    const int d   = dst[e];
    const int pos = atomicAdd(&bins[d], 1);
    binned[pos] = make_int2(src[e], __float_as_int(ew[e]));
}

// ---------------------------------------------------------------------------
// Gather-reduce over bf16 n: one wave per dst; lane covers feats {2l, 2l+1}.
// Writes agg (fp32) pre-divided by clamp(sum_w, 1).
// ---------------------------------------------------------------------------
__global__ __launch_bounds__(256) void gather_agg(
    const __hip_bfloat16* __restrict__ nsrc, const int2* __restrict__ binned,
    const int* __restrict__ bins, float* __restrict__ agg, int N)
{
    const int lane = threadIdx.x & 63;
    const int d    = blockIdx.x * 4 + (threadIdx.x >> 6);
    if (d >= N) return;
    const int lo = (d == 0) ? 0 : bins[d - 1];
    const int hi = bins[d];
    float2 acc = make_float2(0.f, 0.f);
    float  ws  = 0.f;
    int p = lo;
    for (; p + 1 < hi; p += 2) {
        const int2 sw0 = binned[p];
        const int2 sw1 = binned[p + 1];
        const unsigned int u0 = *(const unsigned int*)&nsrc[(size_t)sw0.x * DIM + lane * 2];
        const unsigned int u1 = *(const unsigned int*)&nsrc[(size_t)sw1.x * DIM + lane * 2];
        const float w0 = __int_as_float(sw0.y);
        const float w1 = __int_as_float(sw1.y);
        acc.x = fmaf(__uint_as_float(u0 << 16), w0, acc.x);
        acc.y = fmaf(__uint_as_float(u0 & 0xffff0000u), w0, acc.y);
        acc.x = fmaf(__uint_as_float(u1 << 16), w1, acc.x);
        acc.y = fmaf(__uint_as_float(u1 & 0xffff0000u), w1, acc.y);
        ws += w0 + w1;
    }
    if (p < hi) {
        const int2 sw = binned[p];
        const float w = __int_as_float(sw.y);
        const unsigned int u = *(const unsigned int*)&nsrc[(size_t)sw.x * DIM + lane * 2];
        acc.x = fmaf(__uint_as_float(u << 16), w, acc.x);
        acc.y = fmaf(__uint_as_float(u & 0xffff0000u), w, acc.y);
        ws += w;
    }
    const float inv = 1.f / fmaxf(ws, 1.f);
    float2 o; o.x = acc.x * inv; o.y = acc.y * inv;
    *(float2*)&agg[(size_t)d * DIM + lane * 2] = o;
}

// ---------------------------------------------------------------------------
// GEMM1: n = relu(A @ Q^T + qb), n written as bf16.
// 128x128 block, 256 threads, 8x8/thread. Transposed LDS: At[k][row], Qt[k][col].
// ---------------------------------------------------------------------------
__global__ __launch_bounds__(256) void qgemm_relu(
    const float* __restrict__ A, const float* __restrict__ Q,
    const float* __restrict__ qb, __hip_bfloat16* __restrict__ out, int N)
{
    __shared__ float At[32][PAD];
    __shared__ float Wt[32][PAD];
    const int tid = threadIdx.x;
    const int cg = tid & 15, rg = tid >> 4;
    const int r0 = blockIdx.x * 128;

    float acc[8][8] = {};
    for (int c = 0; c < 4; c++) {
        __syncthreads();
        for (int f4 = tid; f4 < 1024; f4 += 256) {
            const int row = f4 >> 3, k4 = f4 & 7;
            float4 t = make_float4(0.f, 0.f, 0.f, 0.f);
            if (r0 + row < N)
                t = *(const float4*)&A[(size_t)(r0 + row) * DIM + c * 32 + k4 * 4];
            At[k4 * 4 + 0][row] = t.x; At[k4 * 4 + 1][row] = t.y;
            At[k4 * 4 + 2][row] = t.z; At[k4 * 4 + 3][row] = t.w;
            const float4 q = *(const float4*)&Q[(size_t)row * DIM + c * 32 + k4 * 4];
            Wt[k4 * 4 + 0][row] = q.x; Wt[k4 * 4 + 1][row] = q.y;
            Wt[k4 * 4 + 2][row] = q.z; Wt[k4 * 4 + 3][row] = q.w;
        }
        __syncthreads();
        #pragma unroll 2
        for (int k = 0; k < 32; k++) {
            float a[8], w[8];
            *(float4*)&a[0] = *(const float4*)&At[k][rg * 8];
            *(float4*)&a[4] = *(const float4*)&At[k][rg * 8 + 4];
            *(float4*)&w[0] = *(const float4*)&Wt[k][cg * 8];
            *(float4*)&w[4] = *(const float4*)&Wt[k][cg * 8 + 4];
            #pragma unroll
            for (int i = 0; i < 8; i++)
                #pragma unroll
                for (int j = 0; j < 8; j++)
                    acc[i][j] = fmaf(a[i], w[j], acc[i][j]);
        }
    }

    float b[8];
    *(float4*)&b[0] = *(const float4*)&qb[cg * 8];
    *(float4*)&b[4] = *(const float4*)&qb[cg * 8 + 4];
    #pragma unroll
    for (int i = 0; i < 8; i++) {
        const int r = r0 + rg * 8 + i;
        if (r >= N) continue;
        union { unsigned short us[8]; uint4 v; } o;
        #pragma unroll
        for (int j = 0; j < 8; j++)
            o.us[j] = f2bf(fmaxf(acc[i][j] + b[j], 0.f));
        *(uint4*)&out[(size_t)r * DIM + cg * 8] = o.v;
    }
}

// ---------------------------------------------------------------------------
// GEMM2 + epilogue: z = relu([agg, h] @ W^T + wb); out = z / ||z||.
// 128x128 block, 8x8/thread, transposed LDS; K=256 in 8 chunks (agg then h).
// ---------------------------------------------------------------------------
__global__ __launch_bounds__(256) void wgemm_norm(
    const float* __restrict__ agg, const float* __restrict__ h,
    const float* __restrict__ W, const float* __restrict__ wb,
    float* __restrict__ out, int N)
{
    __shared__ float At[32][PAD];
    __shared__ float Wt[32][PAD];
    const int tid = threadIdx.x;
    const int cg = tid & 15, rg = tid >> 4;
    const int r0 = blockIdx.x * 128;

    float acc[8][8] = {};
    for (int c = 0; c < 8; c++) {
        const float* __restrict__ Ap = (c < 4) ? agg : h;
        const int kb = (c & 3) * 32;
        __syncthreads();
        for (int f4 = tid; f4 < 1024; f4 += 256) {
            const int row = f4 >> 3, k4 = f4 & 7;
            float4 t = make_float4(0.f, 0.f, 0.f, 0.f);
            if (r0 + row < N)
                t = *(const float4*)&Ap[(size_t)(r0 + row) * DIM + kb + k4 * 4];
            At[k4 * 4 + 0][row] = t.x; At[k4 * 4 + 1][row] = t.y;
            At[k4 * 4 + 2][row] = t.z; At[k4 * 4 + 3][row] = t.w;
            const float4 q = *(const float4*)&W[(size_t)row * 256 + c * 32 + k4 * 4];
            Wt[k4 * 4 + 0][row] = q.x; Wt[k4 * 4 + 1][row] = q.y;
            Wt[k4 * 4 + 2][row] = q.z; Wt[k4 * 4 + 3][row] = q.w;
        }
        __syncthreads();
        #pragma unroll 2
        for (int k = 0; k < 32; k++) {
            float a[8], w[8];
            *(float4*)&a[0] = *(const float4*)&At[k][rg * 8];
            *(float4*)&a[4] = *(const float4*)&At[k][rg * 8 + 4];
            *(float4*)&w[0] = *(const float4*)&Wt[k][cg * 8];
            *(float4*)&w[4] = *(const float4*)&Wt[k][cg * 8 + 4];
            #pragma unroll
            for (int i = 0; i < 8; i++)
                #pragma unroll
                for (int j = 0; j < 8; j++)
                    acc[i][j] = fmaf(a[i], w[j], acc[i][j]);
        }
    }

    float b[8];
    *(float4*)&b[0] = *(const float4*)&wb[cg * 8];
    *(float4*)&b[4] = *(const float4*)&wb[cg * 8 + 4];
    #pragma unroll
    for (int i = 0; i < 8; i++) {
        const int r = r0 + rg * 8 + i;
        float z[8];
        float ss = 0.f;
        #pragma unroll
        for (int j = 0; j < 8; j++) {
            z[j] = fmaxf(acc[i][j] + b[j], 0.f);
            ss = fmaf(z[j], z[j], ss);
        }
        // reduce over the 16 lanes sharing this row (lane bits 0..3 = cg)
        #pragma unroll
        for (int m = 1; m < 16; m <<= 1) ss += __shfl_xor(ss, m);
        float zn = sqrtf(ss);
        if (zn == 0.f) zn = 1.f;
        const float rn = 1.f / zn;
        if (r < N) {
            float4 o0, o1;
            o0.x = z[0] * rn; o0.y = z[1] * rn; o0.z = z[2] * rn; o0.w = z[3] * rn;
            o1.x = z[4] * rn; o1.y = z[5] * rn; o1.z = z[6] * rn; o1.w = z[7] * rn;
            *(float4*)&out[(size_t)r * DIM + cg * 8]     = o0;
            *(float4*)&out[(size_t)r * DIM + cg * 8 + 4] = o1;
        }
    }
}

extern "C" void kernel_launch(void* const* d_in, const int* in_sizes, int n_in,
                              void* d_out, int out_size, void* d_ws, size_t ws_size,
                              hipStream_t stream) {
    const float* h0  = (const float*)d_in[0];
    const float* ew  = (const float*)d_in[1];
    const float* Qw  = (const float*)d_in[2];
    const float* Qb  = (const float*)d_in[3];
    const float* Ww  = (const float*)d_in[4];
    const float* Wb  = (const float*)d_in[5];
    const int*  esrc = (const int*)d_in[6];
    const int*  edst = (const int*)d_in[7];
    float* out = (float*)d_out;

    __hip_bfloat16* nbuf = (__hip_bfloat16*)d_ws;                   // 12.8 MB
    float* agg    = (float*)(nbuf + (size_t)N_NODES * DIM);         // 25.6 MB
    int*   bins   = (int*)(agg + (size_t)N_NODES * DIM);            // 0.2 MB
    int2*  binned = (int2*)(bins + N_NODES);                        // 6.4 MB
    int*   bsums  = (int*)(binned + N_EDGES);

    const int gemm_blocks = (N_NODES + 127) / 128;   // 391
    const int edge_blocks = (N_EDGES + 255) / 256;
    const int gath_blocks = (N_NODES + 3) / 4;
    const int scan_blocks_n = (N_NODES + 255) / 256; // 196

    for (int l = 0; l < 2; l++) {
        const float* hin = (l == 0) ? h0 : out;
        const int*   src = esrc + (size_t)l * N_EDGES;
        const int*   dst = edst + (size_t)l * N_EDGES;
        const float* w   = ew + (size_t)l * N_EDGES;

        hipMemsetAsync(bins, 0, N_NODES * sizeof(int), stream);
        hist_dst<<<edge_blocks, 256, 0, stream>>>(dst, bins, N_EDGES);
        scan_blocks<<<scan_blocks_n, 256, 0, stream>>>(bins, bsums, N_NODES);
        scan_bsums<<<1, 256, 0, stream>>>(bsums, scan_blocks_n);
        scan_add<<<scan_blocks_n, 256, 0, stream>>>(bins, bsums, N_NODES);
        bin_edges<<<edge_blocks, 256, 0, stream>>>(src, dst, w, bins, binned, N_EDGES);
        qgemm_relu<<<gemm_blocks, 256, 0, stream>>>(
            hin, Qw + (size_t)l * DIM * DIM, Qb + (size_t)l * DIM, nbuf, N_NODES);
        gather_agg<<<gath_blocks, 256, 0, stream>>>(nbuf, binned, bins, agg, N_NODES);
        wgemm_norm<<<gemm_blocks, 256, 0, stream>>>(
            agg, hin, Ww + (size_t)l * DIM * 2 * DIM, Wb + (size_t)l * DIM,
            out, N_NODES);
    }
}

// Round 8
// 565.954 us; speedup vs baseline: 1.1298x; 1.1298x over previous
//
#include <hip/hip_runtime.h>
#include <hip/hip_bf16.h>

#define N_NODES 50000
#define N_EDGES 800000
#define DIM 128
// column swizzle within a 32xk LDS tile: multiple of 4 -> float4 blocks survive
#define SWZ(k) ((((k) >> 2) & 7) << 2)

static __device__ __forceinline__ unsigned short f2bf(float f) {
    unsigned int u = __float_as_uint(f);
    u += 0x7fffu + ((u >> 16) & 1u);  // round-to-nearest-even
    return (unsigned short)(u >> 16);
}

// ---------------------------------------------------------------------------
// Edge binning: histogram -> parallel exclusive scan -> bin scatter.
// ---------------------------------------------------------------------------
__global__ __launch_bounds__(256) void hist_dst(
    const int* __restrict__ dst, int* __restrict__ bins, int E)
{
    const int e = blockIdx.x * 256 + threadIdx.x;
    if (e < E) atomicAdd(&bins[dst[e]], 1);
}

__global__ __launch_bounds__(256) void scan_blocks(
    int* __restrict__ data, int* __restrict__ bsums, int n)
{
    __shared__ int ws[4];
    const int tid = threadIdx.x, lane = tid & 63, wid = tid >> 6;
    const int i = blockIdx.x * 256 + tid;
    const int x = (i < n) ? data[i] : 0;
    int v = x;
    #pragma unroll
    for (int off = 1; off < 64; off <<= 1) {
        const int t = __shfl_up(v, off);
        if (lane >= off) v += t;
    }
    if (lane == 63) ws[wid] = v;
    __syncthreads();
    const int w0 = ws[0], w1 = ws[1], w2 = ws[2];
    const int woff = (wid > 0 ? w0 : 0) + (wid > 1 ? w1 : 0) + (wid > 2 ? w2 : 0);
    const int incl = v + woff;
    if (i < n) data[i] = incl - x;
    if (tid == 255) bsums[blockIdx.x] = incl;
}

__global__ __launch_bounds__(256) void scan_bsums(int* __restrict__ bsums, int nb)
{
    __shared__ int ws[4];
    const int tid = threadIdx.x, lane = tid & 63, wid = tid >> 6;
    const int x = (tid < nb) ? bsums[tid] : 0;
    int v = x;
    #pragma unroll
    for (int off = 1; off < 64; off <<= 1) {
        const int t = __shfl_up(v, off);
        if (lane >= off) v += t;
    }
    if (lane == 63) ws[wid] = v;
    __syncthreads();
    const int w0 = ws[0], w1 = ws[1], w2 = ws[2];
    const int woff = (wid > 0 ? w0 : 0) + (wid > 1 ? w1 : 0) + (wid > 2 ? w2 : 0);
    if (tid < nb) bsums[tid] = (v + woff) - x;
}

__global__ __launch_bounds__(256) void scan_add(
    int* __restrict__ data, const int* __restrict__ bsums, int n)
{
    const int i = blockIdx.x * 256 + threadIdx.x;
    if (i < n) data[i] += bsums[blockIdx.x];
}

__global__ __launch_bounds__(256) void bin_edges(
    const int* __restrict__ src, const int* __restrict__ dst,
    const float* __restrict__ ew, int* __restrict__ bins,
    int2* __restrict__ binned, int E)
{
    const int e = blockIdx.x * 256 + threadIdx.x;
    if (e >= E) return;
    const int d   = dst[e];
    const int pos = atomicAdd(&bins[d], 1);
    binned[pos] = make_int2(src[e], __float_as_int(ew[e]));
}

// ---------------------------------------------------------------------------
// Gather-reduce over bf16 n: one wave per dst; lane covers feats {2l, 2l+1}.
// Writes agg (fp32) pre-divided by clamp(sum_w, 1).
// ---------------------------------------------------------------------------
__global__ __launch_bounds__(256) void gather_agg(
    const __hip_bfloat16* __restrict__ nsrc, const int2* __restrict__ binned,
    const int* __restrict__ bins, float* __restrict__ agg, int N)
{
    const int lane = threadIdx.x & 63;
    const int d    = blockIdx.x * 4 + (threadIdx.x >> 6);
    if (d >= N) return;
    const int lo = (d == 0) ? 0 : bins[d - 1];
    const int hi = bins[d];
    float2 acc = make_float2(0.f, 0.f);
    float  ws  = 0.f;
    int p = lo;
    for (; p + 1 < hi; p += 2) {
        const int2 sw0 = binned[p];
        const int2 sw1 = binned[p + 1];
        const unsigned int u0 = *(const unsigned int*)&nsrc[(size_t)sw0.x * DIM + lane * 2];
        const unsigned int u1 = *(const unsigned int*)&nsrc[(size_t)sw1.x * DIM + lane * 2];
        const float w0 = __int_as_float(sw0.y);
        const float w1 = __int_as_float(sw1.y);
        acc.x = fmaf(__uint_as_float(u0 << 16), w0, acc.x);
        acc.y = fmaf(__uint_as_float(u0 & 0xffff0000u), w0, acc.y);
        acc.x = fmaf(__uint_as_float(u1 << 16), w1, acc.x);
        acc.y = fmaf(__uint_as_float(u1 & 0xffff0000u), w1, acc.y);
        ws += w0 + w1;
    }
    if (p < hi) {
        const int2 sw = binned[p];
        const float w = __int_as_float(sw.y);
        const unsigned int u = *(const unsigned int*)&nsrc[(size_t)sw.x * DIM + lane * 2];
        acc.x = fmaf(__uint_as_float(u << 16), w, acc.x);
        acc.y = fmaf(__uint_as_float(u & 0xffff0000u), w, acc.y);
        ws += w;
    }
    const float inv = 1.f / fmaxf(ws, 1.f);
    float2 o; o.x = acc.x * inv; o.y = acc.y * inv;
    *(float2*)&agg[(size_t)d * DIM + lane * 2] = o;
}

// ---------------------------------------------------------------------------
// Shared GEMM tile machinery: 128x128 block, 256 threads as 16(rg) x 16(cg),
// each thread owns rows {rg*4+i, 64+rg*4+i} x cols {cg*4+j, 64+cg*4+j}.
// LDS transposed + XOR-swizzled: element (k, idx) at T[k][idx ^ SWZ(k)].
// Stage-writes are 2-way (free); fragment reads are contiguous/balanced.
// ---------------------------------------------------------------------------

// GEMM1: n = relu(A @ Q^T + qb), n written as bf16. K = 128.
__global__ __launch_bounds__(256) void qgemm_relu(
    const float* __restrict__ A, const float* __restrict__ Q,
    const float* __restrict__ qb, __hip_bfloat16* __restrict__ out, int N)
{
    __shared__ float At[32][DIM];
    __shared__ float Wt[32][DIM];
    const int tid = threadIdx.x;
    const int cg = tid & 15, rg = tid >> 4;
    const int r0 = blockIdx.x * 128;

    float acc[8][8] = {};
    for (int c = 0; c < 4; c++) {
        __syncthreads();
        for (int f4 = tid; f4 < 1024; f4 += 256) {
            const int row = f4 >> 3, k4 = f4 & 7;
            float4 t = make_float4(0.f, 0.f, 0.f, 0.f);
            if (r0 + row < N)
                t = *(const float4*)&A[(size_t)(r0 + row) * DIM + c * 32 + k4 * 4];
            At[k4 * 4 + 0][row ^ SWZ(k4 * 4 + 0)] = t.x;
            At[k4 * 4 + 1][row ^ SWZ(k4 * 4 + 1)] = t.y;
            At[k4 * 4 + 2][row ^ SWZ(k4 * 4 + 2)] = t.z;
            At[k4 * 4 + 3][row ^ SWZ(k4 * 4 + 3)] = t.w;
            const float4 q = *(const float4*)&Q[(size_t)row * DIM + c * 32 + k4 * 4];
            Wt[k4 * 4 + 0][row ^ SWZ(k4 * 4 + 0)] = q.x;
            Wt[k4 * 4 + 1][row ^ SWZ(k4 * 4 + 1)] = q.y;
            Wt[k4 * 4 + 2][row ^ SWZ(k4 * 4 + 2)] = q.z;
            Wt[k4 * 4 + 3][row ^ SWZ(k4 * 4 + 3)] = q.w;
        }
        __syncthreads();
        #pragma unroll 4
        for (int k = 0; k < 32; k++) {
            const int s = SWZ(k);
            float a[8], w[8];
            *(float4*)&a[0] = *(const float4*)&At[k][(rg * 4) ^ s];
            *(float4*)&a[4] = *(const float4*)&At[k][(64 + rg * 4) ^ s];
            *(float4*)&w[0] = *(const float4*)&Wt[k][(cg * 4) ^ s];
            *(float4*)&w[4] = *(const float4*)&Wt[k][(64 + cg * 4) ^ s];
            #pragma unroll
            for (int i = 0; i < 8; i++)
                #pragma unroll
                for (int j = 0; j < 8; j++)
                    acc[i][j] = fmaf(a[i], w[j], acc[i][j]);
        }
    }

    float b[8];
    *(float4*)&b[0] = *(const float4*)&qb[cg * 4];
    *(float4*)&b[4] = *(const float4*)&qb[64 + cg * 4];
    #pragma unroll
    for (int half = 0; half < 2; half++) {
        #pragma unroll
        for (int i = 0; i < 4; i++) {
            const int r = r0 + half * 64 + rg * 4 + i;
            if (r >= N) continue;
            const int ai = half * 4 + i;
            union { unsigned short us[4]; uint2 v; } o0, o1;
            #pragma unroll
            for (int j = 0; j < 4; j++) {
                o0.us[j] = f2bf(fmaxf(acc[ai][j] + b[j], 0.f));
                o1.us[j] = f2bf(fmaxf(acc[ai][4 + j] + b[4 + j], 0.f));
            }
            *(uint2*)&out[(size_t)r * DIM + cg * 4]      = o0.v;
            *(uint2*)&out[(size_t)r * DIM + 64 + cg * 4] = o1.v;
        }
    }
}

// GEMM2 + epilogue: z = relu([agg, h] @ W^T + wb); out = z / ||z||. K = 256.
__global__ __launch_bounds__(256) void wgemm_norm(
    const float* __restrict__ agg, const float* __restrict__ h,
    const float* __restrict__ W, const float* __restrict__ wb,
    float* __restrict__ out, int N)
{
    __shared__ float At[32][DIM];
    __shared__ float Wt[32][DIM];
    const int tid = threadIdx.x;
    const int cg = tid & 15, rg = tid >> 4;
    const int r0 = blockIdx.x * 128;

    float acc[8][8] = {};
    for (int c = 0; c < 8; c++) {
        const float* __restrict__ Ap = (c < 4) ? agg : h;
        const int kb = (c & 3) * 32;
        __syncthreads();
        for (int f4 = tid; f4 < 1024; f4 += 256) {
            const int row = f4 >> 3, k4 = f4 & 7;
            float4 t = make_float4(0.f, 0.f, 0.f, 0.f);
            if (r0 + row < N)
                t = *(const float4*)&Ap[(size_t)(r0 + row) * DIM + kb + k4 * 4];
            At[k4 * 4 + 0][row ^ SWZ(k4 * 4 + 0)] = t.x;
            At[k4 * 4 + 1][row ^ SWZ(k4 * 4 + 1)] = t.y;
            At[k4 * 4 + 2][row ^ SWZ(k4 * 4 + 2)] = t.z;
            At[k4 * 4 + 3][row ^ SWZ(k4 * 4 + 3)] = t.w;
            const float4 q = *(const float4*)&W[(size_t)row * 256 + c * 32 + k4 * 4];
            Wt[k4 * 4 + 0][row ^ SWZ(k4 * 4 + 0)] = q.x;
            Wt[k4 * 4 + 1][row ^ SWZ(k4 * 4 + 1)] = q.y;
            Wt[k4 * 4 + 2][row ^ SWZ(k4 * 4 + 2)] = q.z;
            Wt[k4 * 4 + 3][row ^ SWZ(k4 * 4 + 3)] = q.w;
        }
        __syncthreads();
        #pragma unroll 4
        for (int k = 0; k < 32; k++) {
            const int s = SWZ(k);
            float a[8], w[8];
            *(float4*)&a[0] = *(const float4*)&At[k][(rg * 4) ^ s];
            *(float4*)&a[4] = *(const float4*)&At[k][(64 + rg * 4) ^ s];
            *(float4*)&w[0] = *(const float4*)&Wt[k][(cg * 4) ^ s];
            *(float4*)&w[4] = *(const float4*)&Wt[k][(64 + cg * 4) ^ s];
            #pragma unroll
            for (int i = 0; i < 8; i++)
                #pragma unroll
                for (int j = 0; j < 8; j++)
                    acc[i][j] = fmaf(a[i], w[j], acc[i][j]);
        }
    }

    float b[8];
    *(float4*)&b[0] = *(const float4*)&wb[cg * 4];
    *(float4*)&b[4] = *(const float4*)&wb[64 + cg * 4];
    #pragma unroll
    for (int half = 0; half < 2; half++) {
        #pragma unroll
        for (int i = 0; i < 4; i++) {
            const int r = r0 + half * 64 + rg * 4 + i;
            const int ai = half * 4 + i;
            float z[8];
            float ss = 0.f;
            #pragma unroll
            for (int j = 0; j < 8; j++) {
                z[j] = fmaxf(acc[ai][j] + b[j], 0.f);
                ss = fmaf(z[j], z[j], ss);
            }
            // reduce across the 16 lanes (bits 0..3 = cg) sharing this row
            #pragma unroll
            for (int m = 1; m < 16; m <<= 1) ss += __shfl_xor(ss, m);
            float zn = sqrtf(ss);
            if (zn == 0.f) zn = 1.f;
            const float rn = 1.f / zn;
            if (r < N) {
                float4 o0, o1;
                o0.x = z[0] * rn; o0.y = z[1] * rn; o0.z = z[2] * rn; o0.w = z[3] * rn;
                o1.x = z[4] * rn; o1.y = z[5] * rn; o1.z = z[6] * rn; o1.w = z[7] * rn;
                *(float4*)&out[(size_t)r * DIM + cg * 4]      = o0;
                *(float4*)&out[(size_t)r * DIM + 64 + cg * 4] = o1;
            }
        }
    }
}

extern "C" void kernel_launch(void* const* d_in, const int* in_sizes, int n_in,
                              void* d_out, int out_size, void* d_ws, size_t ws_size,
                              hipStream_t stream) {
    const float* h0  = (const float*)d_in[0];
    const float* ew  = (const float*)d_in[1];
    const float* Qw  = (const float*)d_in[2];
    const float* Qb  = (const float*)d_in[3];
    const float* Ww  = (const float*)d_in[4];
    const float* Wb  = (const float*)d_in[5];
    const int*  esrc = (const int*)d_in[6];
    const int*  edst = (const int*)d_in[7];
    float* out = (float*)d_out;

    __hip_bfloat16* nbuf = (__hip_bfloat16*)d_ws;                   // 12.8 MB
    float* agg    = (float*)(nbuf + (size_t)N_NODES * DIM);         // 25.6 MB
    int*   bins   = (int*)(agg + (size_t)N_NODES * DIM);            // 0.2 MB
    int2*  binned = (int2*)(bins + N_NODES);                        // 6.4 MB
    int*   bsums  = (int*)(binned + N_EDGES);

    const int gemm_blocks = (N_NODES + 127) / 128;   // 391
    const int edge_blocks = (N_EDGES + 255) / 256;
    const int gath_blocks = (N_NODES + 3) / 4;
    const int scan_blocks_n = (N_NODES + 255) / 256; // 196

    for (int l = 0; l < 2; l++) {
        const float* hin = (l == 0) ? h0 : out;
        const int*   src = esrc + (size_t)l * N_EDGES;
        const int*   dst = edst + (size_t)l * N_EDGES;
        const float* w   = ew + (size_t)l * N_EDGES;

        hipMemsetAsync(bins, 0, N_NODES * sizeof(int), stream);
        hist_dst<<<edge_blocks, 256, 0, stream>>>(dst, bins, N_EDGES);
        scan_blocks<<<scan_blocks_n, 256, 0, stream>>>(bins, bsums, N_NODES);
        scan_bsums<<<1, 256, 0, stream>>>(bsums, scan_blocks_n);
        scan_add<<<scan_blocks_n, 256, 0, stream>>>(bins, bsums, N_NODES);
        bin_edges<<<edge_blocks, 256, 0, stream>>>(src, dst, w, bins, binned, N_EDGES);
        qgemm_relu<<<gemm_blocks, 256, 0, stream>>>(
            hin, Qw + (size_t)l * DIM * DIM, Qb + (size_t)l * DIM, nbuf, N_NODES);
        gather_agg<<<gath_blocks, 256, 0, stream>>>(nbuf, binned, bins, agg, N_NODES);
        wgemm_norm<<<gemm_blocks, 256, 0, stream>>>(
            agg, hin, Ww + (size_t)l * DIM * 2 * DIM, Wb + (size_t)l * DIM,
            out, N_NODES);
    }
}

// Round 9
// 437.230 us; speedup vs baseline: 1.4625x; 1.2944x over previous
//
#include <hip/hip_runtime.h>
#include <hip/hip_bf16.h>

#define N_NODES 50000
#define N_EDGES 800000
#define DIM 128

typedef __attribute__((ext_vector_type(8))) short bf16x8;
typedef __attribute__((ext_vector_type(4))) float f32x4;

static __device__ __forceinline__ unsigned short f2bf(float f) {
    unsigned int u = __float_as_uint(f);
    u += 0x7fffu + ((u >> 16) & 1u);  // round-to-nearest-even
    return (unsigned short)(u >> 16);
}

// ---------------------------------------------------------------------------
// Edge binning: histogram -> parallel exclusive scan -> bin scatter.
// ---------------------------------------------------------------------------
__global__ __launch_bounds__(256) void hist_dst(
    const int* __restrict__ dst, int* __restrict__ bins, int E)
{
    const int e = blockIdx.x * 256 + threadIdx.x;
    if (e < E) atomicAdd(&bins[dst[e]], 1);
}

__global__ __launch_bounds__(256) void scan_blocks(
    int* __restrict__ data, int* __restrict__ bsums, int n)
{
    __shared__ int ws[4];
    const int tid = threadIdx.x, lane = tid & 63, wid = tid >> 6;
    const int i = blockIdx.x * 256 + tid;
    const int x = (i < n) ? data[i] : 0;
    int v = x;
    #pragma unroll
    for (int off = 1; off < 64; off <<= 1) {
        const int t = __shfl_up(v, off);
        if (lane >= off) v += t;
    }
    if (lane == 63) ws[wid] = v;
    __syncthreads();
    const int w0 = ws[0], w1 = ws[1], w2 = ws[2];
    const int woff = (wid > 0 ? w0 : 0) + (wid > 1 ? w1 : 0) + (wid > 2 ? w2 : 0);
    const int incl = v + woff;
    if (i < n) data[i] = incl - x;
    if (tid == 255) bsums[blockIdx.x] = incl;
}

__global__ __launch_bounds__(256) void scan_bsums(int* __restrict__ bsums, int nb)
{
    __shared__ int ws[4];
    const int tid = threadIdx.x, lane = tid & 63, wid = tid >> 6;
    const int x = (tid < nb) ? bsums[tid] : 0;
    int v = x;
    #pragma unroll
    for (int off = 1; off < 64; off <<= 1) {
        const int t = __shfl_up(v, off);
        if (lane >= off) v += t;
    }
    if (lane == 63) ws[wid] = v;
    __syncthreads();
    const int w0 = ws[0], w1 = ws[1], w2 = ws[2];
    const int woff = (wid > 0 ? w0 : 0) + (wid > 1 ? w1 : 0) + (wid > 2 ? w2 : 0);
    if (tid < nb) bsums[tid] = (v + woff) - x;
}

__global__ __launch_bounds__(256) void scan_add(
    int* __restrict__ data, const int* __restrict__ bsums, int n)
{
    const int i = blockIdx.x * 256 + threadIdx.x;
    if (i < n) data[i] += bsums[blockIdx.x];
}

__global__ __launch_bounds__(256) void bin_edges(
    const int* __restrict__ src, const int* __restrict__ dst,
    const float* __restrict__ ew, int* __restrict__ bins,
    int2* __restrict__ binned, int E)
{
    const int e = blockIdx.x * 256 + threadIdx.x;
    if (e >= E) return;
    const int d   = dst[e];
    const int pos = atomicAdd(&bins[d], 1);
    binned[pos] = make_int2(src[e], __float_as_int(ew[e]));
}

// ---------------------------------------------------------------------------
// Gather-reduce over bf16 n: one wave per dst; lane covers feats {2l, 2l+1}.
// Writes agg (fp32) pre-divided by clamp(sum_w, 1).
// ---------------------------------------------------------------------------
__global__ __launch_bounds__(256) void gather_agg(
    const __hip_bfloat16* __restrict__ nsrc, const int2* __restrict__ binned,
    const int* __restrict__ bins, float* __restrict__ agg, int N)
{
    const int lane = threadIdx.x & 63;
    const int d    = blockIdx.x * 4 + (threadIdx.x >> 6);
    if (d >= N) return;
    const int lo = (d == 0) ? 0 : bins[d - 1];
    const int hi = bins[d];
    float2 acc = make_float2(0.f, 0.f);
    float  ws  = 0.f;
    int p = lo;
    for (; p + 1 < hi; p += 2) {
        const int2 sw0 = binned[p];
        const int2 sw1 = binned[p + 1];
        const unsigned int u0 = *(const unsigned int*)&nsrc[(size_t)sw0.x * DIM + lane * 2];
        const unsigned int u1 = *(const unsigned int*)&nsrc[(size_t)sw1.x * DIM + lane * 2];
        const float w0 = __int_as_float(sw0.y);
        const float w1 = __int_as_float(sw1.y);
        acc.x = fmaf(__uint_as_float(u0 << 16), w0, acc.x);
        acc.y = fmaf(__uint_as_float(u0 & 0xffff0000u), w0, acc.y);
        acc.x = fmaf(__uint_as_float(u1 << 16), w1, acc.x);
        acc.y = fmaf(__uint_as_float(u1 & 0xffff0000u), w1, acc.y);
        ws += w0 + w1;
    }
    if (p < hi) {
        const int2 sw = binned[p];
        const float w = __int_as_float(sw.y);
        const unsigned int u = *(const unsigned int*)&nsrc[(size_t)sw.x * DIM + lane * 2];
        acc.x = fmaf(__uint_as_float(u << 16), w, acc.x);
        acc.y = fmaf(__uint_as_float(u & 0xffff0000u), w, acc.y);
        ws += w;
    }
    const float inv = 1.f / fmaxf(ws, 1.f);
    float2 o; o.x = acc.x * inv; o.y = acc.y * inv;
    *(float2*)&agg[(size_t)d * DIM + lane * 2] = o;
}

// ---------------------------------------------------------------------------
// MFMA GEMM machinery: 128x128 tile, 256 threads = 4 waves; wave wv owns rows
// [wv*32, wv*32+32) x all 128 cols as 2x8 fragments of 16x16 (K=32 steps).
// LDS bf16, 8-elem-group XOR swizzle: elem (row,k) at [row][(g^(row&7))*8+k%8],
// g=k>>3 -> fragment reads are 2-way bank-balanced (free), 64KB total.
// A/B frag mapping: row|col = lane&15, k = (lane>>4)*8+i.
// C/D mapping (HW-verified): col = lane&15, row = (lane>>4)*4+reg.
// ---------------------------------------------------------------------------

// GEMM1: n = relu(A @ Q^T + qb) -> bf16. K = 128.
__global__ __launch_bounds__(256) void qgemm_relu(
    const float* __restrict__ A, const float* __restrict__ Q,
    const float* __restrict__ qb, __hip_bfloat16* __restrict__ out, int N)
{
    __shared__ unsigned short Al[128][128];
    __shared__ unsigned short Bl[128][128];
    const int tid = threadIdx.x;
    const int lane = tid & 63, wv = tid >> 6;
    const int lc = lane & 15, lk = lane >> 4;
    const int r0 = blockIdx.x * 128;

    for (int id = tid; id < 2048; id += 256) {
        const int row = id >> 4, g = id & 15;
        const int k8 = g * 8, gs = (g ^ (row & 7)) * 8;
        union { unsigned short us[8]; uint4 v; } a, b;
        if (r0 + row < N) {
            const float4 t0 = *(const float4*)&A[(size_t)(r0 + row) * DIM + k8];
            const float4 t1 = *(const float4*)&A[(size_t)(r0 + row) * DIM + k8 + 4];
            a.us[0] = f2bf(t0.x); a.us[1] = f2bf(t0.y); a.us[2] = f2bf(t0.z); a.us[3] = f2bf(t0.w);
            a.us[4] = f2bf(t1.x); a.us[5] = f2bf(t1.y); a.us[6] = f2bf(t1.z); a.us[7] = f2bf(t1.w);
        } else {
            a.v = make_uint4(0, 0, 0, 0);
        }
        *(uint4*)&Al[row][gs] = a.v;
        const float4 q0 = *(const float4*)&Q[(size_t)row * DIM + k8];
        const float4 q1 = *(const float4*)&Q[(size_t)row * DIM + k8 + 4];
        b.us[0] = f2bf(q0.x); b.us[1] = f2bf(q0.y); b.us[2] = f2bf(q0.z); b.us[3] = f2bf(q0.w);
        b.us[4] = f2bf(q1.x); b.us[5] = f2bf(q1.y); b.us[6] = f2bf(q1.z); b.us[7] = f2bf(q1.w);
        *(uint4*)&Bl[row][gs] = b.v;
    }
    __syncthreads();

    f32x4 acc[2][8];
    #pragma unroll
    for (int rf = 0; rf < 2; rf++)
        #pragma unroll
        for (int cf = 0; cf < 8; cf++)
            acc[rf][cf] = (f32x4){0.f, 0.f, 0.f, 0.f};

    #pragma unroll
    for (int ks = 0; ks < 4; ks++) {
        bf16x8 af[2], bfr[8];
        #pragma unroll
        for (int rf = 0; rf < 2; rf++) {
            const int row = wv * 32 + rf * 16 + lc;
            af[rf] = *(const bf16x8*)&Al[row][((ks * 4 + lk) ^ (row & 7)) * 8];
        }
        #pragma unroll
        for (int cf = 0; cf < 8; cf++) {
            const int col = cf * 16 + lc;
            bfr[cf] = *(const bf16x8*)&Bl[col][((ks * 4 + lk) ^ (col & 7)) * 8];
        }
        #pragma unroll
        for (int rf = 0; rf < 2; rf++)
            #pragma unroll
            for (int cf = 0; cf < 8; cf++)
                acc[rf][cf] = __builtin_amdgcn_mfma_f32_16x16x32_bf16(
                    af[rf], bfr[cf], acc[rf][cf], 0, 0, 0);
    }

    float bias[8];
    #pragma unroll
    for (int cf = 0; cf < 8; cf++) bias[cf] = qb[cf * 16 + lc];
    unsigned short* o16 = (unsigned short*)out;
    #pragma unroll
    for (int rf = 0; rf < 2; rf++)
        #pragma unroll
        for (int reg = 0; reg < 4; reg++) {
            const int r = r0 + wv * 32 + rf * 16 + lk * 4 + reg;
            if (r >= N) continue;
            #pragma unroll
            for (int cf = 0; cf < 8; cf++)
                o16[(size_t)r * DIM + cf * 16 + lc] =
                    f2bf(fmaxf(acc[rf][cf][reg] + bias[cf], 0.f));
        }
}

// GEMM2 + epilogue: z = relu([agg, h] @ W^T + wb); out = z/||z||. K = 256.
__global__ __launch_bounds__(256) void wgemm_norm(
    const float* __restrict__ agg, const float* __restrict__ h,
    const float* __restrict__ W, const float* __restrict__ wb,
    float* __restrict__ out, int N)
{
    __shared__ unsigned short Al[128][128];
    __shared__ unsigned short Bl[128][128];
    const int tid = threadIdx.x;
    const int lane = tid & 63, wv = tid >> 6;
    const int lc = lane & 15, lk = lane >> 4;
    const int r0 = blockIdx.x * 128;

    f32x4 acc[2][8];
    #pragma unroll
    for (int rf = 0; rf < 2; rf++)
        #pragma unroll
        for (int cf = 0; cf < 8; cf++)
            acc[rf][cf] = (f32x4){0.f, 0.f, 0.f, 0.f};

    for (int part = 0; part < 2; part++) {
        const float* __restrict__ Ap = part ? h : agg;
        if (part) __syncthreads();  // previous part's LDS reads done
        for (int id = tid; id < 2048; id += 256) {
            const int row = id >> 4, g = id & 15;
            const int k8 = g * 8, gs = (g ^ (row & 7)) * 8;
            union { unsigned short us[8]; uint4 v; } a, b;
            if (r0 + row < N) {
                const float4 t0 = *(const float4*)&Ap[(size_t)(r0 + row) * DIM + k8];
                const float4 t1 = *(const float4*)&Ap[(size_t)(r0 + row) * DIM + k8 + 4];
                a.us[0] = f2bf(t0.x); a.us[1] = f2bf(t0.y); a.us[2] = f2bf(t0.z); a.us[3] = f2bf(t0.w);
                a.us[4] = f2bf(t1.x); a.us[5] = f2bf(t1.y); a.us[6] = f2bf(t1.z); a.us[7] = f2bf(t1.w);
            } else {
                a.v = make_uint4(0, 0, 0, 0);
            }
            *(uint4*)&Al[row][gs] = a.v;
            const float4 q0 = *(const float4*)&W[(size_t)row * 256 + part * 128 + k8];
            const float4 q1 = *(const float4*)&W[(size_t)row * 256 + part * 128 + k8 + 4];
            b.us[0] = f2bf(q0.x); b.us[1] = f2bf(q0.y); b.us[2] = f2bf(q0.z); b.us[3] = f2bf(q0.w);
            b.us[4] = f2bf(q1.x); b.us[5] = f2bf(q1.y); b.us[6] = f2bf(q1.z); b.us[7] = f2bf(q1.w);
            *(uint4*)&Bl[row][gs] = b.v;
        }
        __syncthreads();

        #pragma unroll
        for (int ks = 0; ks < 4; ks++) {
            bf16x8 af[2], bfr[8];
            #pragma unroll
            for (int rf = 0; rf < 2; rf++) {
                const int row = wv * 32 + rf * 16 + lc;
                af[rf] = *(const bf16x8*)&Al[row][((ks * 4 + lk) ^ (row & 7)) * 8];
            }
            #pragma unroll
            for (int cf = 0; cf < 8; cf++) {
                const int col = cf * 16 + lc;
                bfr[cf] = *(const bf16x8*)&Bl[col][((ks * 4 + lk) ^ (col & 7)) * 8];
            }
            #pragma unroll
            for (int rf = 0; rf < 2; rf++)
                #pragma unroll
                for (int cf = 0; cf < 8; cf++)
                    acc[rf][cf] = __builtin_amdgcn_mfma_f32_16x16x32_bf16(
                        af[rf], bfr[cf], acc[rf][cf], 0, 0, 0);
        }
    }

    float bias[8];
    #pragma unroll
    for (int cf = 0; cf < 8; cf++) bias[cf] = wb[cf * 16 + lc];
    #pragma unroll
    for (int rf = 0; rf < 2; rf++)
        #pragma unroll
        for (int reg = 0; reg < 4; reg++) {
            const int r = r0 + wv * 32 + rf * 16 + lk * 4 + reg;
            float z[8];
            float ss = 0.f;
            #pragma unroll
            for (int cf = 0; cf < 8; cf++) {
                z[cf] = fmaxf(acc[rf][cf][reg] + bias[cf], 0.f);
                ss = fmaf(z[cf], z[cf], ss);
            }
            #pragma unroll
            for (int m = 1; m < 16; m <<= 1) ss += __shfl_xor(ss, m);
            float zn = sqrtf(ss);
            if (zn == 0.f) zn = 1.f;
            const float rn = 1.f / zn;
            if (r < N) {
                #pragma unroll
                for (int cf = 0; cf < 8; cf++)
                    out[(size_t)r * DIM + cf * 16 + lc] = z[cf] * rn;
            }
        }
}

extern "C" void kernel_launch(void* const* d_in, const int* in_sizes, int n_in,
                              void* d_out, int out_size, void* d_ws, size_t ws_size,
                              hipStream_t stream) {
    const float* h0  = (const float*)d_in[0];
    const float* ew  = (const float*)d_in[1];
    const float* Qw  = (const float*)d_in[2];
    const float* Qb  = (const float*)d_in[3];
    const float* Ww  = (const float*)d_in[4];
    const float* Wb  = (const float*)d_in[5];
    const int*  esrc = (const int*)d_in[6];
    const int*  edst = (const int*)d_in[7];
    float* out = (float*)d_out;

    __hip_bfloat16* nbuf = (__hip_bfloat16*)d_ws;                   // 12.8 MB
    float* agg    = (float*)(nbuf + (size_t)N_NODES * DIM);         // 25.6 MB
    int*   bins   = (int*)(agg + (size_t)N_NODES * DIM);            // 0.2 MB
    int2*  binned = (int2*)(bins + N_NODES);                        // 6.4 MB
    int*   bsums  = (int*)(binned + N_EDGES);

    const int gemm_blocks = (N_NODES + 127) / 128;   // 391
    const int edge_blocks = (N_EDGES + 255) / 256;
    const int gath_blocks = (N_NODES + 3) / 4;
    const int scan_blocks_n = (N_NODES + 255) / 256; // 196

    for (int l = 0; l < 2; l++) {
        const float* hin = (l == 0) ? h0 : out;
        const int*   src = esrc + (size_t)l * N_EDGES;
        const int*   dst = edst + (size_t)l * N_EDGES;
        const float* w   = ew + (size_t)l * N_EDGES;

        hipMemsetAsync(bins, 0, N_NODES * sizeof(int), stream);
        hist_dst<<<edge_blocks, 256, 0, stream>>>(dst, bins, N_EDGES);
        scan_blocks<<<scan_blocks_n, 256, 0, stream>>>(bins, bsums, N_NODES);
        scan_bsums<<<1, 256, 0, stream>>>(bsums, scan_blocks_n);
        scan_add<<<scan_blocks_n, 256, 0, stream>>>(bins, bsums, N_NODES);
        bin_edges<<<edge_blocks, 256, 0, stream>>>(src, dst, w, bins, binned, N_EDGES);
        qgemm_relu<<<gemm_blocks, 256, 0, stream>>>(
            hin, Qw + (size_t)l * DIM * DIM, Qb + (size_t)l * DIM, nbuf, N_NODES);
        gather_agg<<<gath_blocks, 256, 0, stream>>>(nbuf, binned, bins, agg, N_NODES);
        wgemm_norm<<<gemm_blocks, 256, 0, stream>>>(
            agg, hin, Ww + (size_t)l * DIM * 2 * DIM, Wb + (size_t)l * DIM,
            out, N_NODES);
    }
}

// Round 10
// 396.754 us; speedup vs baseline: 1.6117x; 1.1020x over previous
//
#include <hip/hip_runtime.h>
#include <hip/hip_bf16.h>

#define N_NODES 50000
#define N_EDGES 800000
#define DIM 128

typedef __attribute__((ext_vector_type(8))) short bf16x8;
typedef __attribute__((ext_vector_type(4))) float f32x4;

static __device__ __forceinline__ unsigned short f2bf(float f) {
    unsigned int u = __float_as_uint(f);
    u += 0x7fffu + ((u >> 16) & 1u);  // round-to-nearest-even
    return (unsigned short)(u >> 16);
}
static __device__ __forceinline__ float bflo(unsigned int u) {
    return __uint_as_float(u << 16);
}
static __device__ __forceinline__ float bfhi(unsigned int u) {
    return __uint_as_float(u & 0xffff0000u);
}

// ---------------------------------------------------------------------------
// fp32 -> bf16 bulk convert (pre-pass; rounding identical to GEMM staging)
// ---------------------------------------------------------------------------
__global__ __launch_bounds__(256) void cvt_f32_bf16(
    const float* __restrict__ in, unsigned short* __restrict__ out, int n)
{
    int i = (blockIdx.x * 256 + threadIdx.x) * 4;
    if (i + 3 < n) {
        const float4 t = *(const float4*)&in[i];
        union { unsigned short us[4]; uint2 v; } o;
        o.us[0] = f2bf(t.x); o.us[1] = f2bf(t.y);
        o.us[2] = f2bf(t.z); o.us[3] = f2bf(t.w);
        *(uint2*)&out[i] = o.v;
    } else {
        for (; i < n; i++) out[i] = f2bf(in[i]);
    }
}

// ---------------------------------------------------------------------------
// Edge binning: histogram -> parallel exclusive scan -> bin scatter.
// ---------------------------------------------------------------------------
__global__ __launch_bounds__(256) void hist_dst(
    const int* __restrict__ dst, int* __restrict__ bins, int E)
{
    const int e = blockIdx.x * 256 + threadIdx.x;
    if (e < E) atomicAdd(&bins[dst[e]], 1);
}

__global__ __launch_bounds__(256) void scan_blocks(
    int* __restrict__ data, int* __restrict__ bsums, int n)
{
    __shared__ int ws[4];
    const int tid = threadIdx.x, lane = tid & 63, wid = tid >> 6;
    const int i = blockIdx.x * 256 + tid;
    const int x = (i < n) ? data[i] : 0;
    int v = x;
    #pragma unroll
    for (int off = 1; off < 64; off <<= 1) {
        const int t = __shfl_up(v, off);
        if (lane >= off) v += t;
    }
    if (lane == 63) ws[wid] = v;
    __syncthreads();
    const int w0 = ws[0], w1 = ws[1], w2 = ws[2];
    const int woff = (wid > 0 ? w0 : 0) + (wid > 1 ? w1 : 0) + (wid > 2 ? w2 : 0);
    const int incl = v + woff;
    if (i < n) data[i] = incl - x;
    if (tid == 255) bsums[blockIdx.x] = incl;
}

__global__ __launch_bounds__(256) void scan_bsums(int* __restrict__ bsums, int nb)
{
    __shared__ int ws[4];
    const int tid = threadIdx.x, lane = tid & 63, wid = tid >> 6;
    const int x = (tid < nb) ? bsums[tid] : 0;
    int v = x;
    #pragma unroll
    for (int off = 1; off < 64; off <<= 1) {
        const int t = __shfl_up(v, off);
        if (lane >= off) v += t;
    }
    if (lane == 63) ws[wid] = v;
    __syncthreads();
    const int w0 = ws[0], w1 = ws[1], w2 = ws[2];
    const int woff = (wid > 0 ? w0 : 0) + (wid > 1 ? w1 : 0) + (wid > 2 ? w2 : 0);
    if (tid < nb) bsums[tid] = (v + woff) - x;
}

__global__ __launch_bounds__(256) void scan_add(
    int* __restrict__ data, const int* __restrict__ bsums, int n)
{
    const int i = blockIdx.x * 256 + threadIdx.x;
    if (i < n) data[i] += bsums[blockIdx.x];
}

__global__ __launch_bounds__(256) void bin_edges(
    const int* __restrict__ src, const int* __restrict__ dst,
    const float* __restrict__ ew, int* __restrict__ bins,
    int2* __restrict__ binned, int E)
{
    const int e = blockIdx.x * 256 + threadIdx.x;
    if (e >= E) return;
    const int d   = dst[e];
    const int pos = atomicAdd(&bins[d], 1);
    binned[pos] = make_int2(src[e], __float_as_int(ew[e]));
}

// ---------------------------------------------------------------------------
// Gather-reduce over bf16 n: one wave per dst; lane covers feats {2l, 2l+1}.
// 4-edge unroll. Writes agg as bf16, pre-divided by clamp(sum_w, 1).
// ---------------------------------------------------------------------------
__global__ __launch_bounds__(256) void gather_agg(
    const unsigned short* __restrict__ nsrc, const int2* __restrict__ binned,
    const int* __restrict__ bins, unsigned short* __restrict__ agg, int N)
{
    const int lane = threadIdx.x & 63;
    const int d    = blockIdx.x * 4 + (threadIdx.x >> 6);
    if (d >= N) return;
    const int lo = (d == 0) ? 0 : bins[d - 1];
    const int hi = bins[d];
    float accx = 0.f, accy = 0.f, ws = 0.f;
    int p = lo;
    for (; p + 3 < hi; p += 4) {
        const int2 s0 = binned[p],     s1 = binned[p + 1];
        const int2 s2 = binned[p + 2], s3 = binned[p + 3];
        const unsigned int u0 = *(const unsigned int*)&nsrc[(size_t)s0.x * DIM + lane * 2];
        const unsigned int u1 = *(const unsigned int*)&nsrc[(size_t)s1.x * DIM + lane * 2];
        const unsigned int u2 = *(const unsigned int*)&nsrc[(size_t)s2.x * DIM + lane * 2];
        const unsigned int u3 = *(const unsigned int*)&nsrc[(size_t)s3.x * DIM + lane * 2];
        const float w0 = __int_as_float(s0.y), w1 = __int_as_float(s1.y);
        const float w2 = __int_as_float(s2.y), w3 = __int_as_float(s3.y);
        accx = fmaf(bflo(u0), w0, accx); accy = fmaf(bfhi(u0), w0, accy);
        accx = fmaf(bflo(u1), w1, accx); accy = fmaf(bfhi(u1), w1, accy);
        accx = fmaf(bflo(u2), w2, accx); accy = fmaf(bfhi(u2), w2, accy);
        accx = fmaf(bflo(u3), w3, accx); accy = fmaf(bfhi(u3), w3, accy);
        ws += (w0 + w1) + (w2 + w3);
    }
    for (; p < hi; ++p) {
        const int2 sw = binned[p];
        const float w = __int_as_float(sw.y);
        const unsigned int u = *(const unsigned int*)&nsrc[(size_t)sw.x * DIM + lane * 2];
        accx = fmaf(bflo(u), w, accx); accy = fmaf(bfhi(u), w, accy);
        ws += w;
    }
    const float inv = 1.f / fmaxf(ws, 1.f);
    const unsigned int o = ((unsigned int)f2bf(accy * inv) << 16) | f2bf(accx * inv);
    *(unsigned int*)&agg[(size_t)d * DIM + lane * 2] = o;
}

// ---------------------------------------------------------------------------
// MFMA GEMM machinery: 128x128 tile, 4 waves; wave wv owns rows [wv*32,+32).
// All operands bf16 in memory -> staging is pure uint4 copies into swizzled
// LDS: elem (row,k) at [row][(g^(row&7))*8 + k%8], g=k>>3. 0 bank conflicts.
// A/B frag: row|col = lane&15, k = (lane>>4)*8+i. C/D: col=lane&15,
// row=(lane>>4)*4+reg (HW-verified).
// ---------------------------------------------------------------------------

// GEMM1: n = relu(A @ Q^T + qb) -> bf16. K = 128.
__global__ __launch_bounds__(256) void qgemm_relu(
    const unsigned short* __restrict__ A, const unsigned short* __restrict__ Q,
    const float* __restrict__ qb, unsigned short* __restrict__ out, int N)
{
    __shared__ unsigned short Al[128][128];
    __shared__ unsigned short Bl[128][128];
    const int tid = threadIdx.x;
    const int lane = tid & 63, wv = tid >> 6;
    const int lc = lane & 15, lk = lane >> 4;
    const int r0 = blockIdx.x * 128;

    for (int id = tid; id < 2048; id += 256) {
        const int row = id >> 4, g = id & 15;
        const int gs = (g ^ (row & 7)) * 8;
        *(uint4*)&Al[row][gs] = *(const uint4*)&A[(size_t)(r0 + row) * DIM + g * 8];
        *(uint4*)&Bl[row][gs] = *(const uint4*)&Q[(size_t)row * DIM + g * 8];
    }
    __syncthreads();

    f32x4 acc[2][8];
    #pragma unroll
    for (int rf = 0; rf < 2; rf++)
        #pragma unroll
        for (int cf = 0; cf < 8; cf++)
            acc[rf][cf] = (f32x4){0.f, 0.f, 0.f, 0.f};

    #pragma unroll
    for (int ks = 0; ks < 4; ks++) {
        bf16x8 af[2], bfr[8];
        #pragma unroll
        for (int rf = 0; rf < 2; rf++) {
            const int row = wv * 32 + rf * 16 + lc;
            af[rf] = *(const bf16x8*)&Al[row][((ks * 4 + lk) ^ (row & 7)) * 8];
        }
        #pragma unroll
        for (int cf = 0; cf < 8; cf++) {
            const int col = cf * 16 + lc;
            bfr[cf] = *(const bf16x8*)&Bl[col][((ks * 4 + lk) ^ (col & 7)) * 8];
        }
        #pragma unroll
        for (int rf = 0; rf < 2; rf++)
            #pragma unroll
            for (int cf = 0; cf < 8; cf++)
                acc[rf][cf] = __builtin_amdgcn_mfma_f32_16x16x32_bf16(
                    af[rf], bfr[cf], acc[rf][cf], 0, 0, 0);
    }

    float bias[8];
    #pragma unroll
    for (int cf = 0; cf < 8; cf++) bias[cf] = qb[cf * 16 + lc];
    #pragma unroll
    for (int rf = 0; rf < 2; rf++)
        #pragma unroll
        for (int reg = 0; reg < 4; reg++) {
            const int r = r0 + wv * 32 + rf * 16 + lk * 4 + reg;
            if (r >= N) continue;
            #pragma unroll
            for (int cf = 0; cf < 8; cf++)
                out[(size_t)r * DIM + cf * 16 + lc] =
                    f2bf(fmaxf(acc[rf][cf][reg] + bias[cf], 0.f));
        }
}

// GEMM2 + epilogue: z = relu([agg, h] @ W^T + wb); h_next = z/||z||.
// write_out==0: write bf16 into hbuf IN PLACE (each block reads exactly its
// own row range before writing it). write_out==1: write fp32 to out.
__global__ __launch_bounds__(256) void wgemm_norm(
    const unsigned short* __restrict__ agg, unsigned short* __restrict__ hbuf,
    const unsigned short* __restrict__ W, const float* __restrict__ wb,
    float* __restrict__ out, int N, int write_out)
{
    __shared__ unsigned short Al[128][128];
    __shared__ unsigned short Bl[128][128];
    const int tid = threadIdx.x;
    const int lane = tid & 63, wv = tid >> 6;
    const int lc = lane & 15, lk = lane >> 4;
    const int r0 = blockIdx.x * 128;

    f32x4 acc[2][8];
    #pragma unroll
    for (int rf = 0; rf < 2; rf++)
        #pragma unroll
        for (int cf = 0; cf < 8; cf++)
            acc[rf][cf] = (f32x4){0.f, 0.f, 0.f, 0.f};

    for (int part = 0; part < 2; part++) {
        const unsigned short* __restrict__ Ap = part ? hbuf : agg;
        if (part) __syncthreads();  // previous part's LDS reads done
        for (int id = tid; id < 2048; id += 256) {
            const int row = id >> 4, g = id & 15;
            const int gs = (g ^ (row & 7)) * 8;
            *(uint4*)&Al[row][gs] = *(const uint4*)&Ap[(size_t)(r0 + row) * DIM + g * 8];
            *(uint4*)&Bl[row][gs] = *(const uint4*)&W[(size_t)row * 256 + part * 128 + g * 8];
        }
        __syncthreads();

        #pragma unroll
        for (int ks = 0; ks < 4; ks++) {
            bf16x8 af[2], bfr[8];
            #pragma unroll
            for (int rf = 0; rf < 2; rf++) {
                const int row = wv * 32 + rf * 16 + lc;
                af[rf] = *(const bf16x8*)&Al[row][((ks * 4 + lk) ^ (row & 7)) * 8];
            }
            #pragma unroll
            for (int cf = 0; cf < 8; cf++) {
                const int col = cf * 16 + lc;
                bfr[cf] = *(const bf16x8*)&Bl[col][((ks * 4 + lk) ^ (col & 7)) * 8];
            }
            #pragma unroll
            for (int rf = 0; rf < 2; rf++)
                #pragma unroll
                for (int cf = 0; cf < 8; cf++)
                    acc[rf][cf] = __builtin_amdgcn_mfma_f32_16x16x32_bf16(
                        af[rf], bfr[cf], acc[rf][cf], 0, 0, 0);
        }
    }

    float bias[8];
    #pragma unroll
    for (int cf = 0; cf < 8; cf++) bias[cf] = wb[cf * 16 + lc];
    #pragma unroll
    for (int rf = 0; rf < 2; rf++)
        #pragma unroll
        for (int reg = 0; reg < 4; reg++) {
            const int r = r0 + wv * 32 + rf * 16 + lk * 4 + reg;
            float z[8];
            float ss = 0.f;
            #pragma unroll
            for (int cf = 0; cf < 8; cf++) {
                z[cf] = fmaxf(acc[rf][cf][reg] + bias[cf], 0.f);
                ss = fmaf(z[cf], z[cf], ss);
            }
            #pragma unroll
            for (int m = 1; m < 16; m <<= 1) ss += __shfl_xor(ss, m);
            float zn = sqrtf(ss);
            if (zn == 0.f) zn = 1.f;
            const float rn = 1.f / zn;
            if (r < N) {
                if (write_out) {
                    #pragma unroll
                    for (int cf = 0; cf < 8; cf++)
                        out[(size_t)r * DIM + cf * 16 + lc] = z[cf] * rn;
                } else {
                    #pragma unroll
                    for (int cf = 0; cf < 8; cf++)
                        hbuf[(size_t)r * DIM + cf * 16 + lc] = f2bf(z[cf] * rn);
                }
            }
        }
}

extern "C" void kernel_launch(void* const* d_in, const int* in_sizes, int n_in,
                              void* d_out, int out_size, void* d_ws, size_t ws_size,
                              hipStream_t stream) {
    const float* h0  = (const float*)d_in[0];
    const float* ew  = (const float*)d_in[1];
    const float* Qw  = (const float*)d_in[2];
    const float* Qb  = (const float*)d_in[3];
    const float* Ww  = (const float*)d_in[4];
    const float* Wb  = (const float*)d_in[5];
    const int*  esrc = (const int*)d_in[6];
    const int*  edst = (const int*)d_in[7];
    float* out = (float*)d_out;

    unsigned short* hbuf = (unsigned short*)d_ws;            // 6.4M elems
    unsigned short* nbuf = hbuf + (size_t)N_NODES * DIM;     // 6.4M
    unsigned short* aggb = nbuf + (size_t)N_NODES * DIM;     // 6.4M
    unsigned short* qwb  = aggb + (size_t)N_NODES * DIM;     // 32768
    unsigned short* wwb  = qwb + 2 * DIM * DIM;              // 65536
    int*   bins   = (int*)(wwb + 2 * DIM * 2 * DIM);
    int2*  binned = (int2*)(bins + N_NODES);
    int*   bsums  = (int*)(binned + N_EDGES);

    const int gemm_blocks = (N_NODES + 127) / 128;   // 391
    const int edge_blocks = (N_EDGES + 255) / 256;
    const int gath_blocks = (N_NODES + 3) / 4;
    const int scan_blocks_n = (N_NODES + 255) / 256; // 196

    // pre-pass: bf16-ize h0 and weights (rounding identical to old staging)
    cvt_f32_bf16<<<(N_NODES * DIM) / 1024, 256, 0, stream>>>(h0, hbuf, N_NODES * DIM);
    cvt_f32_bf16<<<(2 * DIM * DIM) / 1024, 256, 0, stream>>>(Qw, qwb, 2 * DIM * DIM);
    cvt_f32_bf16<<<(2 * DIM * 2 * DIM) / 1024, 256, 0, stream>>>(Ww, wwb, 2 * DIM * 2 * DIM);

    for (int l = 0; l < 2; l++) {
        const int*   src = esrc + (size_t)l * N_EDGES;
        const int*   dst = edst + (size_t)l * N_EDGES;
        const float* w   = ew + (size_t)l * N_EDGES;

        hipMemsetAsync(bins, 0, N_NODES * sizeof(int), stream);
        hist_dst<<<edge_blocks, 256, 0, stream>>>(dst, bins, N_EDGES);
        scan_blocks<<<scan_blocks_n, 256, 0, stream>>>(bins, bsums, N_NODES);
        scan_bsums<<<1, 256, 0, stream>>>(bsums, scan_blocks_n);
        scan_add<<<scan_blocks_n, 256, 0, stream>>>(bins, bsums, N_NODES);
        bin_edges<<<edge_blocks, 256, 0, stream>>>(src, dst, w, bins, binned, N_EDGES);
        qgemm_relu<<<gemm_blocks, 256, 0, stream>>>(
            hbuf, qwb + (size_t)l * DIM * DIM, Qb + (size_t)l * DIM, nbuf, N_NODES);
        gather_agg<<<gath_blocks, 256, 0, stream>>>(nbuf, binned, bins, aggb, N_NODES);
        wgemm_norm<<<gemm_blocks, 256, 0, stream>>>(
            aggb, hbuf, wwb + (size_t)l * DIM * 2 * DIM, Wb + (size_t)l * DIM,
            out, N_NODES, l == 1 ? 1 : 0);
    }
}